// Round 1
// baseline (216.506 us; speedup 1.0000x reference)
//
#include <hip/hip_runtime.h>
#include <stdint.h>

#define DEVINL __device__ __forceinline__

typedef __attribute__((ext_vector_type(8))) __bf16 bf16x8;
typedef __attribute__((ext_vector_type(4))) float f32x4;
typedef __attribute__((ext_vector_type(16))) float f32x16;
typedef __attribute__((ext_vector_type(4))) int i32x4;
typedef __attribute__((ext_vector_type(8))) int i32x8;

// ---------- helpers ----------
DEVINL unsigned short f2bf(float f) {
  union { float f; unsigned int u; } v; v.f = f;
  unsigned int u = v.u;
  return (unsigned short)((u + 0x7fffu + ((u >> 16) & 1u)) >> 16);  // RNE
}

// float -> OCP e4m3 byte via HW cvt (gfx950 = OCP semantics)
DEVINL unsigned char f2fp8(float f) {
  return (unsigned char)(__builtin_amdgcn_cvt_pk_fp8_f32(f, f, 0, false) & 0xff);
}

DEVINL float sigm(float x) { return __builtin_amdgcn_rcpf(1.f + __expf(-x)); }
// tanh = 1 - 2/(1+e^{2x}); inf-safe both directions.
DEVINL float tanh_(float x) {
  return 1.f - 2.f * __builtin_amdgcn_rcpf(1.f + __expf(2.f * x));
}

// async global->LDS 16B per lane; lds base wave-uniform, HW scatters lane i to base+i*16
#define GLD_LDS16(gptr, lptr)                                                  \
  __builtin_amdgcn_global_load_lds(                                            \
      (__attribute__((address_space(1))) void*)(gptr),                         \
      (__attribute__((address_space(3))) void*)(lptr), 16, 0, 0)

// Stage-before-barrier pipeline: STAGE(k+1) issued BEFORE the top barrier;
// TOPBAR_N waits vmcnt(N) = one stage's loads -> stage k landed, stage k+1
// crosses the barrier in flight. Last iter peels to vmcnt(0).
#define TOPBAR_4 asm volatile("s_waitcnt vmcnt(4) lgkmcnt(0)\n\ts_barrier" ::: "memory")
#define TOPBAR_1 asm volatile("s_waitcnt vmcnt(1) lgkmcnt(0)\n\ts_barrier" ::: "memory")
#define TOPBAR_0 asm volatile("s_waitcnt vmcnt(0) lgkmcnt(0)\n\ts_barrier" ::: "memory")
#define BOTBAR   asm volatile("s_waitcnt lgkmcnt(0)\n\ts_barrier" ::: "memory")

// XOR swizzle, 16B chunks, 4 chunks/row: staging chunk c (tile row=c>>2) takes
// source chunk (c&3)^((c>>3)&3) -- i.e. chunk ^ ((row>>1)&3). This is the
// involution matched by BOTH read sides below (bf16 koff in gemm1/3, and the
// 32-row plo/phi pattern in gemm2); verified conflict-free on paper (all 8
// bank-quad residues hit exactly 8x per ds_read_b128).
DEVINL int swz_col(int c) { return ((c & 3) ^ ((c >> 3) & 3)) * 8; }   // bf16: *8 shorts = 16B
DEVINL int swz16(int c) { return ((c & 3) ^ ((c >> 3) & 3)) * 16; }    // fp8: byte offset

// ---------- fused prep: input concat + weight cvt + hvec, grid-sectioned ----------
__global__ void prep_all(const float* __restrict__ obs, const float* __restrict__ act,
                         const float* __restrict__ W1, const float* __restrict__ Wih,
                         const float* __restrict__ W2, const float* __restrict__ Whh,
                         const float* __restrict__ hid, const float* __restrict__ bhh,
                         const float* __restrict__ bih,
                         unsigned short* __restrict__ A0, unsigned short* __restrict__ W1b,
                         unsigned char* __restrict__ Wih8, unsigned short* __restrict__ W2b,
                         float* __restrict__ hvec) {
  const int bid = blockIdx.x, tid = threadIdx.x;
  if (bid < 2176) {
    // section A: concat(obs, act) -> bf16 [32768, 544]
    const int total = 32768 * 68;
    for (int c = bid * 256 + tid; c < total; c += 2176 * 256) {
      const int b = c / 68, c8 = c % 68;
      const float* src = (c8 < 64) ? (obs + (size_t)b * 512 + c8 * 8)
                                   : (act + (size_t)b * 32 + (c8 - 64) * 8);
      float4 f0 = *(const float4*)src;
      float4 f1 = *(const float4*)(src + 4);
      unsigned short u[8] = {f2bf(f0.x), f2bf(f0.y), f2bf(f0.z), f2bf(f0.w),
                             f2bf(f1.x), f2bf(f1.y), f2bf(f1.z), f2bf(f1.w)};
      *(uint4*)(A0 + (size_t)b * 544 + c8 * 8) = *(uint4*)u;
    }
  } else if (bid < 2176 + 1312) {
    // section B: weight conversion (one float4 per thread)
    const int i = (bid - 2176) * 256 + tid;
    if (i < 69632) {                       // W1 -> bf16
      float4 f = *(const float4*)(W1 + (size_t)i * 4);
      unsigned short u[4] = {f2bf(f.x), f2bf(f.y), f2bf(f.z), f2bf(f.w)};
      *(uint2*)(W1b + (size_t)i * 4) = *(uint2*)u;
    } else if (i < 69632 + 262144) {       // Wih -> fp8 e4m3 x16, PLAIN row-major
      const int off = i - 69632;
      const int row = off >> 7, col0 = (off & 127) * 4;  // 4 consecutive cols
      float4 f = *(const float4*)(Wih + (size_t)off * 4);
      int pk = __builtin_amdgcn_cvt_pk_fp8_f32(f.x * 16.f, f.y * 16.f, 0, false);
      pk = __builtin_amdgcn_cvt_pk_fp8_f32(f.z * 16.f, f.w * 16.f, pk, true);
      *(unsigned int*)(Wih8 + (size_t)row * 512 + col0) = (unsigned int)pk;
    } else {                               // W2 -> bf16
      const int off = i - 331776;
      float4 f = *(const float4*)(W2 + (size_t)off * 4);
      unsigned short u[4] = {f2bf(f.x), f2bf(f.y), f2bf(f.z), f2bf(f.w)};
      *(uint2*)(W2b + (size_t)off * 4) = *(uint2*)u;
    }
  } else {
    // section C: hvec[j] = dot(W_hh[j,:], hid) + b_hh[j] + b_ih[j]
    const int j = (bid - 3488) * 4 + (tid >> 6);
    const int lane = tid & 63;
    const float* w = Whh + (size_t)j * 512;
    float s = 0.f;
    for (int k = lane; k < 512; k += 64) s += w[k] * hid[k];
    for (int off = 32; off; off >>= 1) s += __shfl_down(s, off, 64);
    if (lane == 0) hvec[j] = s + bhh[j] + bih[j];
  }
}

// ---------- GEMM1: X8 = fp8(relu(A0 @ W1^T + b1) * 8), plain row-major ----------
__global__ __launch_bounds__(256, 2) void gemm1_relu(
    const unsigned short* __restrict__ A0,   // [32768,544] bf16
    const unsigned short* __restrict__ W1b,  // [512,544] bf16
    const float* __restrict__ b1,            // [512]
    unsigned char* __restrict__ X8) {        // [32768,512] fp8 (x8, plain)
  constexpr int KT = 17, LD = 544;
  __shared__ __align__(16) unsigned short As[2][128 * 32];  // 16 KB
  __shared__ __align__(16) unsigned short Bs[2][128 * 32];  // 16 KB
  const int tid = threadIdx.x, wave = tid >> 6, lane = tid & 63;
  const int id = blockIdx.x, xcd = id & 7, slot = id >> 3;  // 1024 blocks
  const int m0 = (xcd * 32 + (slot >> 2)) * 128;            // 256 m-tiles
  const int n0 = (slot & 3) * 128;                          // 4 n-tiles
  const int wr = (wave >> 1) * 64, wc = (wave & 1) * 64;
  f32x4 acc[4][4] = {};

  const int c0 = tid, c1 = tid + 256;
  const unsigned short* pA0 = A0 + (size_t)(m0 + (c0 >> 2)) * LD + swz_col(c0);
  const unsigned short* pA1 = A0 + (size_t)(m0 + (c1 >> 2)) * LD + swz_col(c1);
  const unsigned short* pB0 = W1b + (size_t)(n0 + (c0 >> 2)) * LD + swz_col(c0);
  const unsigned short* pB1 = W1b + (size_t)(n0 + (c1 >> 2)) * LD + swz_col(c1);
  const int fr = lane & 15, q = lane >> 4;
  const int koff = (q ^ ((fr >> 1) & 3)) * 8;

#define STAGE1(buf)                                                            \
  do {                                                                         \
    GLD_LDS16(pA0, &As[(buf)][wave * 512]);                                    \
    GLD_LDS16(pA1, &As[(buf)][2048 + wave * 512]);                             \
    GLD_LDS16(pB0, &Bs[(buf)][wave * 512]);                                    \
    GLD_LDS16(pB1, &Bs[(buf)][2048 + wave * 512]);                             \
    pA0 += 32; pA1 += 32; pB0 += 32; pB1 += 32;                                \
  } while (0)

  STAGE1(0);
  for (int kt = 0; kt < KT; ++kt) {
    if (kt + 1 < KT) { STAGE1((kt + 1) & 1); TOPBAR_4; } else { TOPBAR_0; }
    const unsigned short* as = As[kt & 1];
    const unsigned short* bs = Bs[kt & 1];
    bf16x8 a[4], b[4];
#pragma unroll
    for (int i = 0; i < 4; ++i) a[i] = *(const bf16x8*)&as[(wr + i * 16 + fr) * 32 + koff];
#pragma unroll
    for (int j = 0; j < 4; ++j) b[j] = *(const bf16x8*)&bs[(wc + j * 16 + fr) * 32 + koff];
#pragma unroll
    for (int i = 0; i < 4; ++i)
#pragma unroll
      for (int j = 0; j < 4; ++j)
        acc[i][j] = __builtin_amdgcn_mfma_f32_16x16x32_bf16(a[i], b[j], acc[i][j], 0, 0, 0);
    BOTBAR;
  }
#undef STAGE1
  const int rbase = q * 4, cn = fr;
#pragma unroll
  for (int i = 0; i < 4; ++i)
#pragma unroll
    for (int j = 0; j < 4; ++j) {
      const int gn = n0 + wc + j * 16 + cn;
      const float bias = b1[gn];
#pragma unroll
      for (int r = 0; r < 4; ++r) {
        const int gm = m0 + wr + i * 16 + rbase + r;
        float v = acc[i][j][r] + bias;
        v = v > 0.f ? v : 0.f;
        X8[(size_t)gm * 512 + gn] = f2fp8(v * 8.f);
      }
    }
}

// ---------- GEMM2 MX-fp8 32x32x64 (4 gate quadrants) + LSTM epilogue ----------
// A = X8 (x8), B = Wih8 (x16), plain row-major; unit E8M0 scales (0x7f = 2^0);
// acc * (1/128) restores scale. One scaled MFMA covers a whole BK=64 K-step
// per quadrant (was 2x 16x16x32 fp8 at half the rate).
// Operand layout (32x32x64 f8f6f4): lane l holds row l&31, k=(l>>5)*32+[0..31]
// -> 32 consecutive bytes = chunks {2g, 2g+1} of the 4x16B-chunk row, read at
// swizzled positions (c ^ ((row>>1)&3)) matching the unchanged STAGE2 swizzle.
// C/D: col=lane&31, row=(reg&3)+8*(reg>>2)+4*(lane>>5)  (shape-determined).
__global__ __launch_bounds__(256, 3) void gemm2_lstm(
    const unsigned char* __restrict__ X8,    // [32768,512] fp8, plain
    const unsigned char* __restrict__ Wih8,  // [2048,512] fp8, plain
    const float* __restrict__ hvec,          // [2048]
    const float* __restrict__ cell,          // [512]
    unsigned short* __restrict__ H,          // [32768,512] bf16 out
    float* __restrict__ hlast,               // [512] fp32 out
    float* __restrict__ clast) {             // [512] fp32 out
  constexpr int KT = 8;                      // BK = 64
  __shared__ __align__(16) unsigned char As[2][128 * 64];     // 8 KB each buf
  __shared__ __align__(16) unsigned char Bs[2][4 * 32 * 64];  // 8 KB each buf
  const int tid = threadIdx.x, wave = tid >> 6, lane = tid & 63;
  const int id = blockIdx.x, xcd = id & 7, slot = id >> 3;  // 4096 blocks
  const int m0 = (xcd * 32 + (slot >> 4)) * 128;            // 256 m-tiles
  const int n0 = (slot & 15) * 32;                          // 16 quadrant-col tiles
  f32x16 acc[4] = {};                        // one 32x32 frag per gate quadrant

  // A tile: 128 rows x 64B = 512 chunks; B: 4 quads x 32 rows x 64B = 512 chunks.
  // chunk c: A row = c>>2; B quad = c>>7, row = (c>>2)&31; col swizzle = swz16(c).
  const int c0 = tid, c1 = tid + 256;
  const unsigned char* pA0 = X8 + (size_t)(m0 + (c0 >> 2)) * 512 + swz16(c0);
  const unsigned char* pA1 = X8 + (size_t)(m0 + (c1 >> 2)) * 512 + swz16(c1);
  const unsigned char* pB0 =
      Wih8 + (size_t)((c0 >> 7) * 512 + n0 + ((c0 >> 2) & 31)) * 512 + swz16(c0);
  const unsigned char* pB1 =
      Wih8 + (size_t)((c1 >> 7) * 512 + n0 + ((c1 >> 2) & 31)) * 512 + swz16(c1);

  const int r31 = lane & 31, g2 = lane >> 5;
  const int sw = (r31 >> 1) & 3;                              // read-side swizzle
  const int plo = ((2 * g2) ^ sw) * 16, phi = ((2 * g2 + 1) ^ sw) * 16;
  const int arow = (wave * 32 + r31) * 64;                    // wave owns 32 rows
  const int brow = r31 * 64;

#define STAGE2(buf)                                                            \
  do {                                                                         \
    GLD_LDS16(pA0, &As[(buf)][wave * 1024]);                                   \
    GLD_LDS16(pA1, &As[(buf)][4096 + wave * 1024]);                            \
    GLD_LDS16(pB0, &Bs[(buf)][wave * 1024]);                                   \
    GLD_LDS16(pB1, &Bs[(buf)][4096 + wave * 1024]);                            \
    pA0 += 64; pA1 += 64; pB0 += 64; pB1 += 64;                                \
  } while (0)

  STAGE2(0);
  for (int kt = 0; kt < KT; ++kt) {
    if (kt + 1 < KT) { STAGE2((kt + 1) & 1); TOPBAR_4; } else { TOPBAR_0; }
    const unsigned char* as = As[kt & 1];
    const unsigned char* bs = Bs[kt & 1];
    i32x4 alo = *(const i32x4*)&as[arow + plo];
    i32x4 ahi = *(const i32x4*)&as[arow + phi];
    i32x8 a = __builtin_shufflevector(alo, ahi, 0, 1, 2, 3, 4, 5, 6, 7);
    i32x8 b[4];
#pragma unroll
    for (int qd = 0; qd < 4; ++qd) {
      i32x4 blo = *(const i32x4*)&bs[qd * 2048 + brow + plo];
      i32x4 bhi = *(const i32x4*)&bs[qd * 2048 + brow + phi];
      b[qd] = __builtin_shufflevector(blo, bhi, 0, 1, 2, 3, 4, 5, 6, 7);
    }
#pragma unroll
    for (int qd = 0; qd < 4; ++qd)
      acc[qd] = __builtin_amdgcn_mfma_scale_f32_32x32x64_f8f6f4(
          a, b[qd], acc[qd],
          0, 0,                 // cbsz=FP8(A), blgp=FP8(B)
          0, 0x7f7f7f7f,        // opselA, scaleA = 1.0 (E8M0 0x7f)
          0, 0x7f7f7f7f);       // opselB, scaleB = 1.0
    BOTBAR;
  }
#undef STAGE2

  const int gn = n0 + r31;  // column in [0,512)
  const float hv_i = hvec[gn];
  const float hv_f = hvec[gn + 512];
  const float hv_g = hvec[gn + 1024];
  const float hv_o = hvec[gn + 1536];
  const float cprev = cell[gn];
  constexpr float S = 1.f / 128.f;  // undo x8 (X) * x16 (Wih)
#pragma unroll
  for (int rg = 0; rg < 4; ++rg)
#pragma unroll
    for (int rr = 0; rr < 4; ++rr) {
      const int reg = rg * 4 + rr;
      const int gm = m0 + wave * 32 + rr + rg * 8 + g2 * 4;
      float si = sigm(acc[0][reg] * S + hv_i);
      float sf = sigm(acc[1][reg] * S + hv_f);
      float tg = tanh_(acc[2][reg] * S + hv_g);
      float so = sigm(acc[3][reg] * S + hv_o);
      float cnew = sf * cprev + si * tg;
      float hnew = so * tanh_(cnew);
      H[(size_t)gm * 512 + gn] = f2bf(hnew);
      if (gm == 32767) { hlast[gn] = hnew; clast[gn] = cnew; }
    }
}

// ---------- GEMM3: Q = H @ W2^T + b2 (64-row tiles, 512 blocks) ----------
__global__ __launch_bounds__(256, 2) void gemm3(
    const unsigned short* __restrict__ H,    // [32768,512] bf16
    const unsigned short* __restrict__ W2b,  // [32,512] bf16
    const float* __restrict__ b2,            // [32]
    float* __restrict__ Q) {                 // [32768,32] fp32
  constexpr int KT = 16, LDW = 520;
  __shared__ __align__(16) unsigned short As[2][64 * 32];    // 8 KB
  __shared__ __align__(16) unsigned short Ws[32 * LDW];      // 32.5 KB
  const int tid = threadIdx.x, wave = tid >> 6, lane = tid & 63;
  const int id = blockIdx.x;                                 // 512 blocks
  const int m0 = ((id & 7) * 64 + (id >> 3)) * 64;           // 64-row tiles
  for (int c = tid; c < 2048; c += 256) {
    const int row = c >> 6, col8 = c & 63;
    *(uint4*)&Ws[row * LDW + col8 * 8] = *(const uint4*)(W2b + row * 512 + col8 * 8);
  }
  f32x4 acc[2] = {};
  const int c0 = tid;
  const unsigned short* pA0 = H + (size_t)(m0 + (c0 >> 2)) * 512 + swz_col(c0);
  const int fr = lane & 15, q = lane >> 4;
  const int koff = (q ^ ((fr >> 1) & 3)) * 8;

#define STAGE3(buf)                                                            \
  do {                                                                         \
    GLD_LDS16(pA0, &As[(buf)][wave * 512]);                                    \
    pA0 += 32;                                                                 \
  } while (0)

  STAGE3(0);
  for (int kt = 0; kt < KT; ++kt) {
    if (kt + 1 < KT) { STAGE3((kt + 1) & 1); TOPBAR_1; } else { TOPBAR_0; }
    const unsigned short* as = As[kt & 1];
    const int k0 = kt * 32;
    bf16x8 a  = *(const bf16x8*)&as[(wave * 16 + fr) * 32 + koff];
    bf16x8 b0 = *(const bf16x8*)&Ws[fr * LDW + k0 + q * 8];
    bf16x8 b1 = *(const bf16x8*)&Ws[(16 + fr) * LDW + k0 + q * 8];
    acc[0] = __builtin_amdgcn_mfma_f32_16x16x32_bf16(a, b0, acc[0], 0, 0, 0);
    acc[1] = __builtin_amdgcn_mfma_f32_16x16x32_bf16(a, b1, acc[1], 0, 0, 0);
    BOTBAR;
  }
#undef STAGE3
  const int rbase = q * 4;
#pragma unroll
  for (int j = 0; j < 2; ++j) {
    const int gn = j * 16 + fr;
    const float bias = b2[gn];
#pragma unroll
    for (int r = 0; r < 4; ++r) {
      const int gm = m0 + wave * 16 + rbase + r;
      Q[(size_t)gm * 32 + gn] = acc[j][r] + bias;
    }
  }
}

// ---------- launch ----------
extern "C" void kernel_launch(void* const* d_in, const int* in_sizes, int n_in,
                              void* d_out, int out_size, void* d_ws, size_t ws_size,
                              hipStream_t stream) {
  const float* obs  = (const float*)d_in[0];
  const float* act  = (const float*)d_in[1];
  const float* hid  = (const float*)d_in[2];
  const float* cell = (const float*)d_in[3];
  const float* W1   = (const float*)d_in[4];
  const float* b1   = (const float*)d_in[5];
  const float* Wih  = (const float*)d_in[6];
  const float* bih  = (const float*)d_in[7];
  const float* Whh  = (const float*)d_in[8];
  const float* bhh  = (const float*)d_in[9];
  const float* W2   = (const float*)d_in[10];
  const float* b2   = (const float*)d_in[11];
  float* out = (float*)d_out;

  char* ws = (char*)d_ws;
  unsigned short* A0   = (unsigned short*)(ws);              // [B,544] bf16 (35,651,584 B)
  unsigned short* H    = (unsigned short*)(ws);              // alias A0 (dead after gemm1)
  unsigned char*  X8   = (unsigned char*)(ws + 35651584);    // [B,512] fp8 plain (16,777,216 B)
  unsigned short* W1b  = (unsigned short*)(ws + 52428800);   // 557,056 B
  unsigned char*  Wih8 = (unsigned char*)(ws + 52985856);    // 1,048,576 B
  unsigned short* W2b  = (unsigned short*)(ws + 54034432);   // 32,768 B
  float*          hvec = (float*)(ws + 54067200);            // 8,192 B

  prep_all<<<4000, 256, 0, stream>>>(obs, act, W1, Wih, W2, Whh, hid, bhh, bih,
                                     A0, W1b, Wih8, W2b, hvec);
  gemm1_relu<<<1024, 256, 0, stream>>>(A0, W1b, b1, X8);
  gemm2_lstm<<<4096, 256, 0, stream>>>(X8, Wih8, hvec, cell, H,
                                       out + 32768 * 32,
                                       out + 32768 * 32 + 512);
  gemm3<<<512, 256, 0, stream>>>(H, W2b, b2, out);
}